// Round 7
// baseline (302.658 us; speedup 1.0000x reference)
//
#include <hip/hip_runtime.h>

// Problem constants (B=2, C=64, C8=8, H=W=96 -> N=9216)
#define NTOK  9216
#define NBAT  2

typedef __attribute__((ext_vector_type(8))) short bf16x8;
typedef __attribute__((ext_vector_type(4))) float f32x4;

#if __has_builtin(__builtin_amdgcn_exp2f)
#define EXP2(x) __builtin_amdgcn_exp2f(x)
#else
#define EXP2(x) exp2f(x)
#endif
#define L2E 1.4426950408889634f

__device__ __forceinline__ unsigned short f2bf(float x) {
  unsigned int u = __builtin_bit_cast(unsigned int, x);
  u += 0x7fffu + ((u >> 16) & 1u);   // RNE
  return (unsigned short)(u >> 16);
}

// pack two non-negative floats to bf16x2 (round-half-up via +0x8000, v_perm)
__device__ __forceinline__ unsigned int pack_bf2(float lo, float hi) {
  unsigned int ulo = __builtin_bit_cast(unsigned int, lo) + 0x8000u;
  unsigned int uhi = __builtin_bit_cast(unsigned int, hi) + 0x8000u;
  return __builtin_amdgcn_perm(uhi, ulo, 0x07060302u);
}

// ---------------------------------------------------------------------------
// Kernel 1: QKV projections -> bf16.
//   qg[b][n][8]  = (q + bq) * log2(e)   (softmax exp folded into Q scale)
//   kg[b][n][8], vg[b][c][n]
// v2: W rows staged in LDS (coalesced), copied LDS->VGPRs once per wave, so
// the inner loop has NO scalar-memory ops (no lgkm s_load/ds_read mixing) —
// just 1 ds_read_b32 + 4 fmaf per cin.
// ---------------------------------------------------------------------------
__global__ __launch_bounds__(256) void qkv_proj(
    const float* __restrict__ x,
    const float* __restrict__ Wq, const float* __restrict__ bq,
    const float* __restrict__ Wk, const float* __restrict__ bk,
    const float* __restrict__ Wv, const float* __restrict__ bv,
    unsigned short* __restrict__ qg, unsigned short* __restrict__ kg,
    unsigned short* __restrict__ vg)
{
  __shared__ __align__(16) float xl[64 * 68];
  __shared__ __align__(16) float wl[16 * 64];
  __shared__ float bl[16];
  const int bid = blockIdx.x;
  const int rg  = bid % 5;
  const int t2  = bid / 5;
  const int nt  = t2 % 144;
  const int b   = t2 / 144;
  const int t   = threadIdx.x;
  const int lane = t & 63;
  const int n0  = nt * 64;

  // stage this block's 16 W rows (rg*16 .. rg*16+15) + biases
  {
    int grow = rg * 16 + (t >> 4);
    const float* src; int lr;
    if (grow < 8)       { src = Wq; lr = grow; }
    else if (grow < 16) { src = Wk; lr = grow - 8; }
    else                { src = Wv; lr = grow - 16; }
    *(float4*)&wl[(t >> 4) * 64 + (t & 15) * 4] =
        *(const float4*)(src + lr * 64 + (t & 15) * 4);
    if (t < 16) {
      int gr = rg * 16 + t;
      bl[t] = gr < 8 ? bq[gr] : (gr < 16 ? bk[gr - 8] : bv[gr - 16]);
    }
  }
  // stage x tile [64 cin][64 n]
  #pragma unroll
  for (int kk = 0; kk < 4; kk++) {
    int p = t + kk * 256;
    int c = p >> 4, n4 = (p & 15) << 2;
    *(float4*)(&xl[c * 68 + n4]) =
        *(const float4*)(x + (size_t)(b * 64 + c) * NTOK + n0 + n4);
  }
  __syncthreads();

  const int g  = __builtin_amdgcn_readfirstlane(t >> 6);  // wave id 0..3
  const int r0 = rg * 16 + g * 4;                         // rows r0..r0+3

  // W rows LDS -> VGPRs once (uniform-address broadcast b128 reads)
  float4 wr[4][16];
  #pragma unroll
  for (int rr = 0; rr < 4; rr++)
    #pragma unroll
    for (int q4 = 0; q4 < 16; q4++)
      wr[rr][q4] = *(const float4*)&wl[(g * 4 + rr) * 64 + q4 * 4];

  float a0 = 0.f, a1 = 0.f, a2 = 0.f, a3 = 0.f;
  #pragma unroll
  for (int c4 = 0; c4 < 16; c4++) {
    float x0 = xl[(c4 * 4 + 0) * 68 + lane];
    float x1 = xl[(c4 * 4 + 1) * 68 + lane];
    float x2 = xl[(c4 * 4 + 2) * 68 + lane];
    float x3 = xl[(c4 * 4 + 3) * 68 + lane];
    a0 = fmaf(wr[0][c4].x, x0, a0); a0 = fmaf(wr[0][c4].y, x1, a0);
    a0 = fmaf(wr[0][c4].z, x2, a0); a0 = fmaf(wr[0][c4].w, x3, a0);
    a1 = fmaf(wr[1][c4].x, x0, a1); a1 = fmaf(wr[1][c4].y, x1, a1);
    a1 = fmaf(wr[1][c4].z, x2, a1); a1 = fmaf(wr[1][c4].w, x3, a1);
    a2 = fmaf(wr[2][c4].x, x0, a2); a2 = fmaf(wr[2][c4].y, x1, a2);
    a2 = fmaf(wr[2][c4].z, x2, a2); a2 = fmaf(wr[2][c4].w, x3, a2);
    a3 = fmaf(wr[3][c4].x, x0, a3); a3 = fmaf(wr[3][c4].y, x1, a3);
    a3 = fmaf(wr[3][c4].z, x2, a3); a3 = fmaf(wr[3][c4].w, x3, a3);
  }
  a0 += bl[g * 4 + 0]; a1 += bl[g * 4 + 1];
  a2 += bl[g * 4 + 2]; a3 += bl[g * 4 + 3];
  if (r0 < 8) { a0 *= L2E; a1 *= L2E; a2 *= L2E; a3 *= L2E; }  // wave-uniform

  const int n = n0 + lane;
  if (r0 < 16) {
    ushort4 o;
    o.x = f2bf(a0); o.y = f2bf(a1); o.z = f2bf(a2); o.w = f2bf(a3);
    int lr0 = (r0 < 8) ? r0 : r0 - 8;
    unsigned short* dst = (r0 < 8) ? qg : kg;
    *(ushort4*)(dst + ((size_t)b * NTOK + n) * 8 + lr0) = o;
  } else {
    int lr0 = r0 - 16;
    vg[(size_t)(b * 64 + lr0)     * NTOK + n] = f2bf(a0);
    vg[(size_t)(b * 64 + lr0 + 1) * NTOK + n] = f2bf(a1);
    vg[(size_t)(b * 64 + lr0 + 2) * NTOK + n] = f2bf(a2);
    vg[(size_t)(b * 64 + lr0 + 3) * NTOK + n] = f2bf(a3);
  }
}

// ---------------------------------------------------------------------------
// Kernel 2: flash partial + fused last-block merge/epilogue.
// Core identical to r6 (32 rows/wave, pipelined P round-trip, alternating K
// banks). After storing its (O,l) partial, each block fences + bumps a
// per-tile counter; the second arriver reads the sibling slot (agent-scope
// atomic loads -> cross-XCD safe) and writes y = gs*O/L + x.
// ---------------------------------------------------------------------------

#define STAGE(IT_, KFU_, KFP_, JNEXT_)                                        \
  {                                                                           \
    unsigned short* pwb = pb + ((IT_) & 1) * 2304;                            \
    f32x4 st[4];                                                              \
    _Pragma("unroll")                                                         \
    for (int jt = 0; jt < 4; jt++)                                            \
      st[jt] = __builtin_amdgcn_mfma_f32_16x16x32_bf16(KFU_[jt], qf[0], z4, 0, 0, 0); \
    _Pragma("unroll")                                                         \
    for (int jt = 0; jt < 4; jt++)                                            \
      KFP_[jt] = *(const bf16x8*)(kb + ((JNEXT_) + jt * 16) * 8 + koff);      \
    {                                                                         \
      float ps = 0.f;                                                         \
      _Pragma("unroll")                                                       \
      for (int jt = 0; jt < 4; jt++) {                                        \
        float p0 = EXP2(st[jt][0]);                                           \
        float p1 = EXP2(st[jt][1]);                                           \
        float p2 = EXP2(st[jt][2]);                                           \
        float p3 = EXP2(st[jt][3]);                                           \
        ps += (p0 + p1) + (p2 + p3);                                          \
        *(uint2*)(&pwb[i16 * 72 + (((jt * 4 + quad) ^ sw) << 2)]) =           \
            make_uint2(pack_bf2(p0, p1), pack_bf2(p2, p3));                   \
      }                                                                       \
      lp0 += ps;                                                              \
    }                                                                         \
    _Pragma("unroll")                                                         \
    for (int jt = 0; jt < 4; jt++)                                            \
      st[jt] = __builtin_amdgcn_mfma_f32_16x16x32_bf16(KFU_[jt], qf[1], z4, 0, 0, 0); \
    {                                                                         \
      float ps = 0.f;                                                         \
      _Pragma("unroll")                                                       \
      for (int jt = 0; jt < 4; jt++) {                                        \
        float p0 = EXP2(st[jt][0]);                                           \
        float p1 = EXP2(st[jt][1]);                                           \
        float p2 = EXP2(st[jt][2]);                                           \
        float p3 = EXP2(st[jt][3]);                                           \
        ps += (p0 + p1) + (p2 + p3);                                          \
        *(uint2*)(&pwb[(16 + i16) * 72 + (((jt * 4 + quad) ^ sw) << 2)]) =    \
            make_uint2(pack_bf2(p0, p1), pack_bf2(p2, p3));                   \
      }                                                                       \
      lp1 += ps;                                                              \
    }                                                                         \
  }

#define BODY(IT_, KFU_, KFP_)                                                 \
  {                                                                           \
    const int jp = jbase + (((IT_) - 1) << 8);                                \
    const int jn = ((IT_) == 17) ? jbase : jbase + (((IT_) + 1) << 8);        \
    unsigned short* pr = pb + (((IT_) - 1) & 1) * 2304;                       \
    bf16x8 pf[2][2];                                                          \
    _Pragma("unroll")                                                         \
    for (int s = 0; s < 2; s++) {                                             \
      pf[s][0] = *(const bf16x8*)(&pr[(s * 16 + i16) * 72 + (((2 * quad) ^ sw) << 2)]); \
      pf[s][1] = *(const bf16x8*)(&pr[(s * 16 + i16) * 72 + (((8 + 2 * quad) ^ sw) << 2)]); \
    }                                                                         \
    bf16x8 vf0[4];                                                            \
    _Pragma("unroll")                                                         \
    for (int ct = 0; ct < 4; ct++)                                            \
      vf0[ct] = *(const bf16x8*)(vb + ct * 16 * NTOK + voff + jp);            \
    STAGE(IT_, KFU_, KFP_, jn);                                               \
    bf16x8 vf1[4];                                                            \
    _Pragma("unroll")                                                         \
    for (int ct = 0; ct < 4; ct++)                                            \
      vf1[ct] = *(const bf16x8*)(vb + ct * 16 * NTOK + voff + jp + 32);       \
    _Pragma("unroll")                                                         \
    for (int s = 0; s < 2; s++)                                               \
      _Pragma("unroll")                                                       \
      for (int ct = 0; ct < 4; ct++)                                          \
        acc[s][ct] = __builtin_amdgcn_mfma_f32_16x16x32_bf16(vf0[ct], pf[s][0], acc[s][ct], 0, 0, 0); \
    _Pragma("unroll")                                                         \
    for (int s = 0; s < 2; s++)                                               \
      _Pragma("unroll")                                                       \
      for (int ct = 0; ct < 4; ct++)                                          \
        acc[s][ct] = __builtin_amdgcn_mfma_f32_16x16x32_bf16(vf1[ct], pf[s][1], acc[s][ct], 0, 0, 0); \
  }

__global__ __launch_bounds__(256, 3) void flash_partial(
    const float* __restrict__ x,
    const unsigned short* __restrict__ qg,
    const unsigned short* __restrict__ kg,
    const unsigned short* __restrict__ vg,
    const float* __restrict__ gamma_p,
    const float* __restrict__ dyn_p,
    float* __restrict__ opart, float* __restrict__ lpart,
    int* __restrict__ cnt,
    float* __restrict__ y)
{
  __shared__ __align__(16) unsigned short p_lds[4 * 2 * 32 * 72]; // 36864 B
  __shared__ float l_s[4][32];
  __shared__ float lsum_s[32];
  __shared__ int done_s;

  const int bid  = blockIdx.x;
  const int jh   = bid & 1;
  const int tile = bid >> 1;          // b*288 + rt
  const int rt   = tile % 288;
  const int b    = tile / 288;
  const int tid  = threadIdx.x;
  const int w    = tid >> 6;
  const int lane = tid & 63;
  const int i16  = lane & 15;
  const int quad = lane >> 4;
  const int jbase = jh * 4608 + (w << 6);
  const int sw   = (i16 & 3) << 2;          // P-tile granule-XOR swizzle

  unsigned short* pb = &p_lds[w * 4608];

  const unsigned short* __restrict__ vb = vg + (size_t)b * 64 * NTOK;
  const unsigned short* __restrict__ kb = kg + (size_t)b * NTOK * 8;
  const int koff = i16 * 8;
  const int voff = i16 * NTOK + quad * 8;

  bf16x8 qf[2] = {};
  if (quad == 0) {
    qf[0] = *(const bf16x8*)(qg + ((size_t)b * NTOK + rt * 32 + i16) * 8);
    qf[1] = *(const bf16x8*)(qg + ((size_t)b * NTOK + rt * 32 + 16 + i16) * 8);
  }

  f32x4 acc[2][4];
  #pragma unroll
  for (int s = 0; s < 2; s++)
    #pragma unroll
    for (int ct = 0; ct < 4; ct++) acc[s][ct] = (f32x4){0.f, 0.f, 0.f, 0.f};
  float lp0 = 0.f, lp1 = 0.f;
  const f32x4 z4 = {0.f, 0.f, 0.f, 0.f};

  bf16x8 kfA[4], kfB[4];
  #pragma unroll
  for (int jt = 0; jt < 4; jt++)
    kfA[jt] = *(const bf16x8*)(kb + (jbase + jt * 16) * 8 + koff);

  STAGE(0, kfA, kfB, jbase + 256);
  for (int it2 = 0; it2 < 8; ++it2) {
    BODY(2 * it2 + 1, kfB, kfA);
    BODY(2 * it2 + 2, kfA, kfB);
  }
  BODY(17, kfB, kfA);

  // epilogue: PV(17)
  {
    const int jp = jbase + (17 << 8);
    unsigned short* pr = pb + 2304;   // buffer 17&1
    #pragma unroll
    for (int s = 0; s < 2; s++) {
      bf16x8 pf0 = *(const bf16x8*)(&pr[(s * 16 + i16) * 72 + (((2 * quad) ^ sw) << 2)]);
      bf16x8 pf1 = *(const bf16x8*)(&pr[(s * 16 + i16) * 72 + (((8 + 2 * quad) ^ sw) << 2)]);
      #pragma unroll
      for (int ct = 0; ct < 4; ct++) {
        bf16x8 vf0 = *(const bf16x8*)(vb + ct * 16 * NTOK + voff + jp);
        bf16x8 vf1 = *(const bf16x8*)(vb + ct * 16 * NTOK + voff + jp + 32);
        acc[s][ct] = __builtin_amdgcn_mfma_f32_16x16x32_bf16(vf0, pf0, acc[s][ct], 0, 0, 0);
        acc[s][ct] = __builtin_amdgcn_mfma_f32_16x16x32_bf16(vf1, pf1, acc[s][ct], 0, 0, 0);
      }
    }
  }

  lp0 += __shfl_xor(lp0, 16); lp0 += __shfl_xor(lp0, 32);
  lp1 += __shfl_xor(lp1, 16); lp1 += __shfl_xor(lp1, 32);
  if (quad == 0) { l_s[w][i16] = lp0; l_s[w][16 + i16] = lp1; }

  __syncthreads();                 // all P-tile reads done -> overlay obuf
  float* obuf = (float*)p_lds;     // [4][64][33] = 33792 B <= 36864 B
  #pragma unroll
  for (int s = 0; s < 2; s++)
    #pragma unroll
    for (int ct = 0; ct < 4; ct++)
      #pragma unroll
      for (int r = 0; r < 4; r++)
        obuf[w * 2112 + (ct * 16 + quad * 4 + r) * 33 + s * 16 + i16] = acc[s][ct][r];
  if (tid < 32)
    lsum_s[tid] = l_s[0][tid] + l_s[1][tid] + l_s[2][tid] + l_s[3][tid];
  __syncthreads();

  // block partial: keep in regs AND store to this block's slot
  float* ob = opart + (size_t)bid * 2048;
  float myo[8];
  #pragma unroll
  for (int e0 = 0; e0 < 8; e0++) {
    int e = tid + e0 * 256, c = e >> 5, r = e & 31;
    myo[e0] = obuf[c * 33 + r] + obuf[2112 + c * 33 + r]
            + obuf[4224 + c * 33 + r] + obuf[6336 + c * 33 + r];
    ob[e] = myo[e0];
  }
  if (tid < 32) lpart[(size_t)bid * 32 + tid] = lsum_s[tid];

  // ---- last-block-done merge + epilogue
  __threadfence();
  __syncthreads();
  if (tid == 0)
    done_s = __hip_atomic_fetch_add(&cnt[tile], 1, __ATOMIC_ACQ_REL,
                                    __HIP_MEMORY_SCOPE_AGENT);
  __syncthreads();
  if (done_s == 1) {
    const float* oo = opart + (size_t)(bid ^ 1) * 2048;
    const float* ol = lpart + (size_t)(bid ^ 1) * 32;
    const float gs = gamma_p[0] * dyn_p[0];
    const int r = tid & 31;
    float Lo = __hip_atomic_load(&ol[r], __ATOMIC_RELAXED,
                                 __HIP_MEMORY_SCOPE_AGENT);
    float L = Lo + lsum_s[r];
    #pragma unroll
    for (int e0 = 0; e0 < 8; e0++) {
      int e = tid + e0 * 256, c = e >> 5;
      float Oo = __hip_atomic_load(&oo[e], __ATOMIC_RELAXED,
                                   __HIP_MEMORY_SCOPE_AGENT);
      float O = myo[e0] + Oo;
      size_t a = (size_t)(b * 64 + c) * NTOK + rt * 32 + r;
      y[a] = gs * O / L + x[a];
    }
  }
}

// ---------------------------------------------------------------------------
extern "C" void kernel_launch(void* const* d_in, const int* in_sizes, int n_in,
                              void* d_out, int out_size, void* d_ws, size_t ws_size,
                              hipStream_t stream) {
  const float* x     = (const float*)d_in[0];
  const float* Wq    = (const float*)d_in[1];
  const float* bq    = (const float*)d_in[2];
  const float* Wk    = (const float*)d_in[3];
  const float* bk    = (const float*)d_in[4];
  const float* Wv    = (const float*)d_in[5];
  const float* bv    = (const float*)d_in[6];
  const float* gamma = (const float*)d_in[7];
  const float* dyn   = (const float*)d_in[8];
  float* y = (float*)d_out;

  // workspace layout (bf16 then f32/int, 16B-aligned boundaries)
  unsigned short* qg = (unsigned short*)d_ws;              // B*N*8
  unsigned short* kg = qg + (size_t)NBAT * NTOK * 8;       // B*N*8
  unsigned short* vg = kg + (size_t)NBAT * NTOK * 8;       // B*64*N
  float* opart = (float*)(vg + (size_t)NBAT * 64 * NTOK);  // 1152*2048
  float* lpart = opart + (size_t)1152 * 2048;              // 1152*32
  int*   cnt   = (int*)(lpart + (size_t)1152 * 32);        // 576

  hipMemsetAsync(cnt, 0, 576 * sizeof(int), stream);
  qkv_proj<<<NBAT * 144 * 5, 256, 0, stream>>>(x, Wq, bq, Wk, bk, Wv, bv, qg, kg, vg);
  flash_partial<<<NBAT * 288 * 2, 256, 0, stream>>>(x, qg, kg, vg, gamma, dyn,
                                                    opart, lpart, cnt, y);
}

// Round 8
// 191.455 us; speedup vs baseline: 1.5808x; 1.5808x over previous
//
#include <hip/hip_runtime.h>

// Problem constants (B=2, C=64, C8=8, H=W=96 -> N=9216)
#define NTOK  9216
#define NBAT  2

typedef __attribute__((ext_vector_type(8))) short bf16x8;
typedef __attribute__((ext_vector_type(4))) float f32x4;

#if __has_builtin(__builtin_amdgcn_exp2f)
#define EXP2(x) __builtin_amdgcn_exp2f(x)
#else
#define EXP2(x) exp2f(x)
#endif
#define L2E 1.4426950408889634f

__device__ __forceinline__ unsigned short f2bf(float x) {
  unsigned int u = __builtin_bit_cast(unsigned int, x);
  u += 0x7fffu + ((u >> 16) & 1u);   // RNE
  return (unsigned short)(u >> 16);
}

// pack two non-negative floats to bf16x2 (round-half-up via +0x8000, v_perm)
__device__ __forceinline__ unsigned int pack_bf2(float lo, float hi) {
  unsigned int ulo = __builtin_bit_cast(unsigned int, lo) + 0x8000u;
  unsigned int uhi = __builtin_bit_cast(unsigned int, hi) + 0x8000u;
  return __builtin_amdgcn_perm(uhi, ulo, 0x07060302u);
}

// ---------------------------------------------------------------------------
// Kernel 1: QKV projections -> bf16.
//   qg[b][n][8]  = (q + bq) * log2(e)   (softmax exp folded into Q scale)
//   kg[b][n][8], vg[b][c][n]
// W rows staged in LDS (coalesced), copied LDS->VGPRs once per wave, so the
// inner loop has NO scalar-memory ops — 1 ds_read_b32 + 4 fmaf per cin.
// ---------------------------------------------------------------------------
__global__ __launch_bounds__(256) void qkv_proj(
    const float* __restrict__ x,
    const float* __restrict__ Wq, const float* __restrict__ bq,
    const float* __restrict__ Wk, const float* __restrict__ bk,
    const float* __restrict__ Wv, const float* __restrict__ bv,
    unsigned short* __restrict__ qg, unsigned short* __restrict__ kg,
    unsigned short* __restrict__ vg)
{
  __shared__ __align__(16) float xl[64 * 68];
  __shared__ __align__(16) float wl[16 * 64];
  __shared__ float bl[16];
  const int bid = blockIdx.x;
  const int rg  = bid % 5;
  const int t2  = bid / 5;
  const int nt  = t2 % 144;
  const int b   = t2 / 144;
  const int t   = threadIdx.x;
  const int lane = t & 63;
  const int n0  = nt * 64;

  // stage this block's 16 W rows (rg*16 .. rg*16+15) + biases
  {
    int grow = rg * 16 + (t >> 4);
    const float* src; int lr;
    if (grow < 8)       { src = Wq; lr = grow; }
    else if (grow < 16) { src = Wk; lr = grow - 8; }
    else                { src = Wv; lr = grow - 16; }
    *(float4*)&wl[(t >> 4) * 64 + (t & 15) * 4] =
        *(const float4*)(src + lr * 64 + (t & 15) * 4);
    if (t < 16) {
      int gr = rg * 16 + t;
      bl[t] = gr < 8 ? bq[gr] : (gr < 16 ? bk[gr - 8] : bv[gr - 16]);
    }
  }
  // stage x tile [64 cin][64 n]
  #pragma unroll
  for (int kk = 0; kk < 4; kk++) {
    int p = t + kk * 256;
    int c = p >> 4, n4 = (p & 15) << 2;
    *(float4*)(&xl[c * 68 + n4]) =
        *(const float4*)(x + (size_t)(b * 64 + c) * NTOK + n0 + n4);
  }
  __syncthreads();

  const int g  = __builtin_amdgcn_readfirstlane(t >> 6);  // wave id 0..3
  const int r0 = rg * 16 + g * 4;                         // rows r0..r0+3

  // W rows LDS -> VGPRs once (uniform-address broadcast b128 reads)
  float4 wr[4][16];
  #pragma unroll
  for (int rr = 0; rr < 4; rr++)
    #pragma unroll
    for (int q4 = 0; q4 < 16; q4++)
      wr[rr][q4] = *(const float4*)&wl[(g * 4 + rr) * 64 + q4 * 4];

  float a0 = 0.f, a1 = 0.f, a2 = 0.f, a3 = 0.f;
  #pragma unroll
  for (int c4 = 0; c4 < 16; c4++) {
    float x0 = xl[(c4 * 4 + 0) * 68 + lane];
    float x1 = xl[(c4 * 4 + 1) * 68 + lane];
    float x2 = xl[(c4 * 4 + 2) * 68 + lane];
    float x3 = xl[(c4 * 4 + 3) * 68 + lane];
    a0 = fmaf(wr[0][c4].x, x0, a0); a0 = fmaf(wr[0][c4].y, x1, a0);
    a0 = fmaf(wr[0][c4].z, x2, a0); a0 = fmaf(wr[0][c4].w, x3, a0);
    a1 = fmaf(wr[1][c4].x, x0, a1); a1 = fmaf(wr[1][c4].y, x1, a1);
    a1 = fmaf(wr[1][c4].z, x2, a1); a1 = fmaf(wr[1][c4].w, x3, a1);
    a2 = fmaf(wr[2][c4].x, x0, a2); a2 = fmaf(wr[2][c4].y, x1, a2);
    a2 = fmaf(wr[2][c4].z, x2, a2); a2 = fmaf(wr[2][c4].w, x3, a2);
    a3 = fmaf(wr[3][c4].x, x0, a3); a3 = fmaf(wr[3][c4].y, x1, a3);
    a3 = fmaf(wr[3][c4].z, x2, a3); a3 = fmaf(wr[3][c4].w, x3, a3);
  }
  a0 += bl[g * 4 + 0]; a1 += bl[g * 4 + 1];
  a2 += bl[g * 4 + 2]; a3 += bl[g * 4 + 3];
  if (r0 < 8) { a0 *= L2E; a1 *= L2E; a2 *= L2E; a3 *= L2E; }  // wave-uniform

  const int n = n0 + lane;
  if (r0 < 16) {
    ushort4 o;
    o.x = f2bf(a0); o.y = f2bf(a1); o.z = f2bf(a2); o.w = f2bf(a3);
    int lr0 = (r0 < 8) ? r0 : r0 - 8;
    unsigned short* dst = (r0 < 8) ? qg : kg;
    *(ushort4*)(dst + ((size_t)b * NTOK + n) * 8 + lr0) = o;
  } else {
    int lr0 = r0 - 16;
    vg[(size_t)(b * 64 + lr0)     * NTOK + n] = f2bf(a0);
    vg[(size_t)(b * 64 + lr0 + 1) * NTOK + n] = f2bf(a1);
    vg[(size_t)(b * 64 + lr0 + 2) * NTOK + n] = f2bf(a2);
    vg[(size_t)(b * 64 + lr0 + 3) * NTOK + n] = f2bf(a3);
  }
}

// ---------------------------------------------------------------------------
// Kernel 2: flash attention, FULL j-range per block (no split, no partials,
// no fences). Block = 4 waves sharing 32 query rows; wave w covers j-chunks
// {w*64 + it*256}, it<36. r6-proven core: alternating K frag banks,
// pipelined P LDS round-trip (double-buffered, granule-XOR swizzled),
// V frags issued early. Epilogue: 4-wave LDS merge, y = gs*O/L + x direct.
// ---------------------------------------------------------------------------

#define STAGE(IT_, KFU_, KFP_, JNEXT_)                                        \
  {                                                                           \
    unsigned short* pwb = pb + ((IT_) & 1) * 2304;                            \
    f32x4 st[4];                                                              \
    _Pragma("unroll")                                                         \
    for (int jt = 0; jt < 4; jt++)                                            \
      st[jt] = __builtin_amdgcn_mfma_f32_16x16x32_bf16(KFU_[jt], qf[0], z4, 0, 0, 0); \
    _Pragma("unroll")                                                         \
    for (int jt = 0; jt < 4; jt++)                                            \
      KFP_[jt] = *(const bf16x8*)(kb + ((JNEXT_) + jt * 16) * 8 + koff);      \
    {                                                                         \
      float ps = 0.f;                                                         \
      _Pragma("unroll")                                                       \
      for (int jt = 0; jt < 4; jt++) {                                        \
        float p0 = EXP2(st[jt][0]);                                           \
        float p1 = EXP2(st[jt][1]);                                           \
        float p2 = EXP2(st[jt][2]);                                           \
        float p3 = EXP2(st[jt][3]);                                           \
        ps += (p0 + p1) + (p2 + p3);                                          \
        *(uint2*)(&pwb[i16 * 72 + (((jt * 4 + quad) ^ sw) << 2)]) =           \
            make_uint2(pack_bf2(p0, p1), pack_bf2(p2, p3));                   \
      }                                                                       \
      lp0 += ps;                                                              \
    }                                                                         \
    _Pragma("unroll")                                                         \
    for (int jt = 0; jt < 4; jt++)                                            \
      st[jt] = __builtin_amdgcn_mfma_f32_16x16x32_bf16(KFU_[jt], qf[1], z4, 0, 0, 0); \
    {                                                                         \
      float ps = 0.f;                                                         \
      _Pragma("unroll")                                                       \
      for (int jt = 0; jt < 4; jt++) {                                        \
        float p0 = EXP2(st[jt][0]);                                           \
        float p1 = EXP2(st[jt][1]);                                           \
        float p2 = EXP2(st[jt][2]);                                           \
        float p3 = EXP2(st[jt][3]);                                           \
        ps += (p0 + p1) + (p2 + p3);                                          \
        *(uint2*)(&pwb[(16 + i16) * 72 + (((jt * 4 + quad) ^ sw) << 2)]) =    \
            make_uint2(pack_bf2(p0, p1), pack_bf2(p2, p3));                   \
      }                                                                       \
      lp1 += ps;                                                              \
    }                                                                         \
  }

#define BODY(IT_, KFU_, KFP_)                                                 \
  {                                                                           \
    const int jp = jbase + (((IT_) - 1) << 8);                                \
    const int jn = ((IT_) == 35) ? jbase : jbase + (((IT_) + 1) << 8);        \
    unsigned short* pr = pb + (((IT_) - 1) & 1) * 2304;                       \
    bf16x8 pf[2][2];                                                          \
    _Pragma("unroll")                                                         \
    for (int s = 0; s < 2; s++) {                                             \
      pf[s][0] = *(const bf16x8*)(&pr[(s * 16 + i16) * 72 + (((2 * quad) ^ sw) << 2)]); \
      pf[s][1] = *(const bf16x8*)(&pr[(s * 16 + i16) * 72 + (((8 + 2 * quad) ^ sw) << 2)]); \
    }                                                                         \
    bf16x8 vf0[4];                                                            \
    _Pragma("unroll")                                                         \
    for (int ct = 0; ct < 4; ct++)                                            \
      vf0[ct] = *(const bf16x8*)(vb + ct * 16 * NTOK + voff + jp);            \
    STAGE(IT_, KFU_, KFP_, jn);                                               \
    bf16x8 vf1[4];                                                            \
    _Pragma("unroll")                                                         \
    for (int ct = 0; ct < 4; ct++)                                            \
      vf1[ct] = *(const bf16x8*)(vb + ct * 16 * NTOK + voff + jp + 32);       \
    _Pragma("unroll")                                                         \
    for (int s = 0; s < 2; s++)                                               \
      _Pragma("unroll")                                                       \
      for (int ct = 0; ct < 4; ct++)                                          \
        acc[s][ct] = __builtin_amdgcn_mfma_f32_16x16x32_bf16(vf0[ct], pf[s][0], acc[s][ct], 0, 0, 0); \
    _Pragma("unroll")                                                         \
    for (int s = 0; s < 2; s++)                                               \
      _Pragma("unroll")                                                       \
      for (int ct = 0; ct < 4; ct++)                                          \
        acc[s][ct] = __builtin_amdgcn_mfma_f32_16x16x32_bf16(vf1[ct], pf[s][1], acc[s][ct], 0, 0, 0); \
  }

__global__ __launch_bounds__(256, 3) void flash_full(
    const float* __restrict__ x,
    const unsigned short* __restrict__ qg,
    const unsigned short* __restrict__ kg,
    const unsigned short* __restrict__ vg,
    const float* __restrict__ gamma_p,
    const float* __restrict__ dyn_p,
    float* __restrict__ y)
{
  __shared__ __align__(16) unsigned short p_lds[4 * 2 * 32 * 72]; // 36864 B
  __shared__ float l_s[4][32];
  __shared__ float lsum_s[32];

  const int bid  = blockIdx.x;
  const int rt   = bid % 288;
  const int b    = bid / 288;
  const int tid  = threadIdx.x;
  const int w    = tid >> 6;
  const int lane = tid & 63;
  const int i16  = lane & 15;
  const int quad = lane >> 4;
  const int jbase = w << 6;
  const int sw   = (i16 & 3) << 2;          // P-tile granule-XOR swizzle

  unsigned short* pb = &p_lds[w * 4608];

  const unsigned short* __restrict__ vb = vg + (size_t)b * 64 * NTOK;
  const unsigned short* __restrict__ kb = kg + (size_t)b * NTOK * 8;
  const int koff = i16 * 8;
  const int voff = i16 * NTOK + quad * 8;

  bf16x8 qf[2] = {};
  if (quad == 0) {
    qf[0] = *(const bf16x8*)(qg + ((size_t)b * NTOK + rt * 32 + i16) * 8);
    qf[1] = *(const bf16x8*)(qg + ((size_t)b * NTOK + rt * 32 + 16 + i16) * 8);
  }

  f32x4 acc[2][4];
  #pragma unroll
  for (int s = 0; s < 2; s++)
    #pragma unroll
    for (int ct = 0; ct < 4; ct++) acc[s][ct] = (f32x4){0.f, 0.f, 0.f, 0.f};
  float lp0 = 0.f, lp1 = 0.f;
  const f32x4 z4 = {0.f, 0.f, 0.f, 0.f};

  bf16x8 kfA[4], kfB[4];
  #pragma unroll
  for (int jt = 0; jt < 4; jt++)
    kfA[jt] = *(const bf16x8*)(kb + (jbase + jt * 16) * 8 + koff);

  STAGE(0, kfA, kfB, jbase + 256);
  for (int it2 = 0; it2 < 17; ++it2) {
    BODY(2 * it2 + 1, kfB, kfA);
    BODY(2 * it2 + 2, kfA, kfB);
  }
  BODY(35, kfB, kfA);

  // epilogue: PV(35)
  {
    const int jp = jbase + (35 << 8);
    unsigned short* pr = pb + 2304;   // buffer 35&1
    #pragma unroll
    for (int s = 0; s < 2; s++) {
      bf16x8 pf0 = *(const bf16x8*)(&pr[(s * 16 + i16) * 72 + (((2 * quad) ^ sw) << 2)]);
      bf16x8 pf1 = *(const bf16x8*)(&pr[(s * 16 + i16) * 72 + (((8 + 2 * quad) ^ sw) << 2)]);
      #pragma unroll
      for (int ct = 0; ct < 4; ct++) {
        bf16x8 vf0 = *(const bf16x8*)(vb + ct * 16 * NTOK + voff + jp);
        bf16x8 vf1 = *(const bf16x8*)(vb + ct * 16 * NTOK + voff + jp + 32);
        acc[s][ct] = __builtin_amdgcn_mfma_f32_16x16x32_bf16(vf0, pf0, acc[s][ct], 0, 0, 0);
        acc[s][ct] = __builtin_amdgcn_mfma_f32_16x16x32_bf16(vf1, pf1, acc[s][ct], 0, 0, 0);
      }
    }
  }

  lp0 += __shfl_xor(lp0, 16); lp0 += __shfl_xor(lp0, 32);
  lp1 += __shfl_xor(lp1, 16); lp1 += __shfl_xor(lp1, 32);
  if (quad == 0) { l_s[w][i16] = lp0; l_s[w][16 + i16] = lp1; }

  __syncthreads();                 // all P-tile reads done -> overlay obuf
  float* obuf = (float*)p_lds;     // [4][64][33] = 33792 B <= 36864 B
  #pragma unroll
  for (int s = 0; s < 2; s++)
    #pragma unroll
    for (int ct = 0; ct < 4; ct++)
      #pragma unroll
      for (int r = 0; r < 4; r++)
        obuf[w * 2112 + (ct * 16 + quad * 4 + r) * 33 + s * 16 + i16] = acc[s][ct][r];
  if (tid < 32)
    lsum_s[tid] = l_s[0][tid] + l_s[1][tid] + l_s[2][tid] + l_s[3][tid];
  __syncthreads();

  // direct epilogue: y = gs*O/L + x  (2048 outputs, 8 per thread)
  const float gs = gamma_p[0] * dyn_p[0];
  #pragma unroll
  for (int e0 = 0; e0 < 8; e0++) {
    int e = tid + e0 * 256, c = e >> 5, r = e & 31;
    float O = obuf[c * 33 + r] + obuf[2112 + c * 33 + r]
            + obuf[4224 + c * 33 + r] + obuf[6336 + c * 33 + r];
    size_t a = (size_t)(b * 64 + c) * NTOK + rt * 32 + r;
    y[a] = gs * O / lsum_s[r] + x[a];
  }
}

// ---------------------------------------------------------------------------
extern "C" void kernel_launch(void* const* d_in, const int* in_sizes, int n_in,
                              void* d_out, int out_size, void* d_ws, size_t ws_size,
                              hipStream_t stream) {
  const float* x     = (const float*)d_in[0];
  const float* Wq    = (const float*)d_in[1];
  const float* bq    = (const float*)d_in[2];
  const float* Wk    = (const float*)d_in[3];
  const float* bk    = (const float*)d_in[4];
  const float* Wv    = (const float*)d_in[5];
  const float* bv    = (const float*)d_in[6];
  const float* gamma = (const float*)d_in[7];
  const float* dyn   = (const float*)d_in[8];
  float* y = (float*)d_out;

  // workspace: qg | kg | vg  (bf16)
  unsigned short* qg = (unsigned short*)d_ws;              // B*N*8
  unsigned short* kg = qg + (size_t)NBAT * NTOK * 8;       // B*N*8
  unsigned short* vg = kg + (size_t)NBAT * NTOK * 8;       // B*64*N

  qkv_proj<<<NBAT * 144 * 5, 256, 0, stream>>>(x, Wq, bq, Wk, bk, Wv, bv, qg, kg, vg);
  flash_full<<<NBAT * 288, 256, 0, stream>>>(x, qg, kg, vg, gamma, dyn, y);
}

// Round 9
// 188.482 us; speedup vs baseline: 1.6058x; 1.0158x over previous
//
#include <hip/hip_runtime.h>

// Problem constants (B=2, C=64, C8=8, H=W=96 -> N=9216)
#define NTOK  9216
#define NBAT  2

typedef __attribute__((ext_vector_type(8))) short bf16x8;
typedef __attribute__((ext_vector_type(4))) float f32x4;

#if __has_builtin(__builtin_amdgcn_exp2f)
#define EXP2(x) __builtin_amdgcn_exp2f(x)
#else
#define EXP2(x) exp2f(x)
#endif
#define L2E 1.4426950408889634f

__device__ __forceinline__ unsigned short f2bf(float x) {
  unsigned int u = __builtin_bit_cast(unsigned int, x);
  u += 0x7fffu + ((u >> 16) & 1u);   // RNE
  return (unsigned short)(u >> 16);
}

// pack two non-negative floats to bf16x2 (round-half-up via +0x8000, v_perm)
__device__ __forceinline__ unsigned int pack_bf2(float lo, float hi) {
  unsigned int ulo = __builtin_bit_cast(unsigned int, lo) + 0x8000u;
  unsigned int uhi = __builtin_bit_cast(unsigned int, hi) + 0x8000u;
  return __builtin_amdgcn_perm(uhi, ulo, 0x07060302u);
}

// ---------------------------------------------------------------------------
// Kernel 1: QKV projections -> bf16 (R2/R3's simple version — cheapest
// measured side-car). qg = (q+bq)*log2e; kg[b][n][8]; vg[b][c][n].
// Grid = B*144 n-tiles * 10 row-groups = 2880 blocks; 2 rows/thread;
// x reads coalesced along n; W rows wave-uniform -> scalar loads.
// ---------------------------------------------------------------------------
__global__ __launch_bounds__(256) void qkv_proj(
    const float* __restrict__ x,
    const float* __restrict__ Wq, const float* __restrict__ bq,
    const float* __restrict__ Wk, const float* __restrict__ bk,
    const float* __restrict__ Wv, const float* __restrict__ bv,
    unsigned short* __restrict__ qg, unsigned short* __restrict__ kg,
    unsigned short* __restrict__ vg)
{
  const int bid = blockIdx.x;
  const int rg  = bid % 10;          // row-group: 8 rows of the 80
  const int t2  = bid / 10;
  const int nt  = t2 % 144;
  const int b   = t2 / 144;
  const int t   = threadIdx.x;
  const int n   = nt * 64 + (t & 63);
  const int g   = t >> 6;            // wave id 0..3 (wave-uniform)
  const int r0  = rg * 8 + g * 2;    // first of this thread's 2 rows (0..79)

  const float *wr0, *wr1;
  float bz0, bz1;
  if (r0 < 8)       { wr0 = Wq + r0 * 64;        bz0 = bq[r0];      bz1 = bq[r0 + 1]; }
  else if (r0 < 16) { wr0 = Wk + (r0 - 8) * 64;  bz0 = bk[r0 - 8];  bz1 = bk[r0 - 7]; }
  else              { wr0 = Wv + (r0 - 16) * 64; bz0 = bv[r0 - 16]; bz1 = bv[r0 - 15]; }
  wr1 = wr0 + 64;

  const float* xc = x + (size_t)b * 64 * NTOK + n;
  float a0 = 0.f, a1 = 0.f;
  #pragma unroll
  for (int c = 0; c < 64; c++) {
    float xv = xc[(size_t)c * NTOK];
    a0 = fmaf(wr0[c], xv, a0);
    a1 = fmaf(wr1[c], xv, a1);
  }
  a0 += bz0; a1 += bz1;
  if (r0 < 8) { a0 *= L2E; a1 *= L2E; }   // fold softmax exp base into Q

  unsigned short o0 = f2bf(a0), o1 = f2bf(a1);
  if (r0 < 8) {
    qg[((size_t)b * NTOK + n) * 8 + r0]     = o0;
    qg[((size_t)b * NTOK + n) * 8 + r0 + 1] = o1;
  } else if (r0 < 16) {
    kg[((size_t)b * NTOK + n) * 8 + r0 - 8] = o0;
    kg[((size_t)b * NTOK + n) * 8 + r0 - 7] = o1;
  } else {
    vg[(size_t)(b * 64 + r0 - 16) * NTOK + n] = o0;
    vg[(size_t)(b * 64 + r0 - 15) * NTOK + n] = o1;
  }
}

// ---------------------------------------------------------------------------
// Kernel 2: flash partial (R6 core: 32 rows/wave, split-j, alternating K frag
// banks, pipelined dbuf P round-trip, granule-XOR swizzle). NEW: the l
// row-sum rides the MFMA pipe (ones·P^T) instead of a VALU add chain —
// STAGE's serial path is exp->pack->write only, and no end-of-loop shfls.
// ---------------------------------------------------------------------------

#define STAGE(IT_, KFU_, KFP_, JNEXT_)                                        \
  {                                                                           \
    unsigned short* pwb = pb + ((IT_) & 1) * 2304;                            \
    f32x4 st[4];                                                              \
    _Pragma("unroll")                                                         \
    for (int jt = 0; jt < 4; jt++)                                            \
      st[jt] = __builtin_amdgcn_mfma_f32_16x16x32_bf16(KFU_[jt], qf[0], z4, 0, 0, 0); \
    _Pragma("unroll")                                                         \
    for (int jt = 0; jt < 4; jt++)                                            \
      KFP_[jt] = *(const bf16x8*)(kb + ((JNEXT_) + jt * 16) * 8 + koff);      \
    _Pragma("unroll")                                                         \
    for (int jt = 0; jt < 4; jt++) {                                          \
      float p0 = EXP2(st[jt][0]);                                             \
      float p1 = EXP2(st[jt][1]);                                             \
      float p2 = EXP2(st[jt][2]);                                             \
      float p3 = EXP2(st[jt][3]);                                             \
      *(uint2*)(&pwb[i16 * 72 + (((jt * 4 + quad) ^ sw) << 2)]) =             \
          make_uint2(pack_bf2(p0, p1), pack_bf2(p2, p3));                     \
    }                                                                         \
    _Pragma("unroll")                                                         \
    for (int jt = 0; jt < 4; jt++)                                            \
      st[jt] = __builtin_amdgcn_mfma_f32_16x16x32_bf16(KFU_[jt], qf[1], z4, 0, 0, 0); \
    _Pragma("unroll")                                                         \
    for (int jt = 0; jt < 4; jt++) {                                          \
      float p0 = EXP2(st[jt][0]);                                             \
      float p1 = EXP2(st[jt][1]);                                             \
      float p2 = EXP2(st[jt][2]);                                             \
      float p3 = EXP2(st[jt][3]);                                             \
      *(uint2*)(&pwb[(16 + i16) * 72 + (((jt * 4 + quad) ^ sw) << 2)]) =      \
          make_uint2(pack_bf2(p0, p1), pack_bf2(p2, p3));                     \
    }                                                                         \
  }

#define BODY(IT_, KFU_, KFP_)                                                 \
  {                                                                           \
    const int jp = jbase + (((IT_) - 1) << 8);                                \
    const int jn = ((IT_) == 17) ? jbase : jbase + (((IT_) + 1) << 8);        \
    unsigned short* pr = pb + (((IT_) - 1) & 1) * 2304;                       \
    bf16x8 pf[2][2];                                                          \
    _Pragma("unroll")                                                         \
    for (int s = 0; s < 2; s++) {                                             \
      pf[s][0] = *(const bf16x8*)(&pr[(s * 16 + i16) * 72 + (((2 * quad) ^ sw) << 2)]); \
      pf[s][1] = *(const bf16x8*)(&pr[(s * 16 + i16) * 72 + (((8 + 2 * quad) ^ sw) << 2)]); \
    }                                                                         \
    bf16x8 vf0[4];                                                            \
    _Pragma("unroll")                                                         \
    for (int ct = 0; ct < 4; ct++)                                            \
      vf0[ct] = *(const bf16x8*)(vb + ct * 16 * NTOK + voff + jp);            \
    STAGE(IT_, KFU_, KFP_, jn);                                               \
    bf16x8 vf1[4];                                                            \
    _Pragma("unroll")                                                         \
    for (int ct = 0; ct < 4; ct++)                                            \
      vf1[ct] = *(const bf16x8*)(vb + ct * 16 * NTOK + voff + jp + 32);       \
    _Pragma("unroll")                                                         \
    for (int s = 0; s < 2; s++) {                                             \
      _Pragma("unroll")                                                       \
      for (int ct = 0; ct < 4; ct++)                                          \
        acc[s][ct] = __builtin_amdgcn_mfma_f32_16x16x32_bf16(vf0[ct], pf[s][0], acc[s][ct], 0, 0, 0); \
      accl[s] = __builtin_amdgcn_mfma_f32_16x16x32_bf16(onef, pf[s][0], accl[s], 0, 0, 0); \
    }                                                                         \
    _Pragma("unroll")                                                         \
    for (int s = 0; s < 2; s++) {                                             \
      _Pragma("unroll")                                                       \
      for (int ct = 0; ct < 4; ct++)                                          \
        acc[s][ct] = __builtin_amdgcn_mfma_f32_16x16x32_bf16(vf1[ct], pf[s][1], acc[s][ct], 0, 0, 0); \
      accl[s] = __builtin_amdgcn_mfma_f32_16x16x32_bf16(onef, pf[s][1], accl[s], 0, 0, 0); \
    }                                                                         \
  }

__global__ __launch_bounds__(256, 3) void flash_partial(
    const unsigned short* __restrict__ qg,
    const unsigned short* __restrict__ kg,
    const unsigned short* __restrict__ vg,
    float* __restrict__ opart, float* __restrict__ lpart)
{
  __shared__ __align__(16) unsigned short p_lds[4 * 2 * 32 * 72]; // 36864 B
  __shared__ float l_s[4][32];

  const int bid  = blockIdx.x;
  const int jh   = bid & 1;
  const int rt   = (bid >> 1) % 288;
  const int b    = (bid >> 1) / 288;
  const int tid  = threadIdx.x;
  const int w    = tid >> 6;
  const int lane = tid & 63;
  const int i16  = lane & 15;
  const int quad = lane >> 4;
  const int jbase = jh * 4608 + (w << 6);
  const int sw   = (i16 & 3) << 2;          // P-tile granule-XOR swizzle

  unsigned short* pb = &p_lds[w * 4608];

  const unsigned short* __restrict__ vb = vg + (size_t)b * 64 * NTOK;
  const unsigned short* __restrict__ kb = kg + (size_t)b * NTOK * 8;
  const int koff = i16 * 8;
  const int voff = i16 * NTOK + quad * 8;

  bf16x8 qf[2] = {};
  if (quad == 0) {
    qf[0] = *(const bf16x8*)(qg + ((size_t)b * NTOK + rt * 32 + i16) * 8);
    qf[1] = *(const bf16x8*)(qg + ((size_t)b * NTOK + rt * 32 + 16 + i16) * 8);
  }

  f32x4 acc[2][4], accl[2];
  #pragma unroll
  for (int s = 0; s < 2; s++) {
    #pragma unroll
    for (int ct = 0; ct < 4; ct++) acc[s][ct] = (f32x4){0.f, 0.f, 0.f, 0.f};
    accl[s] = (f32x4){0.f, 0.f, 0.f, 0.f};
  }
  const f32x4 z4 = {0.f, 0.f, 0.f, 0.f};
  const short one_bf = (short)0x3F80;      // bf16 1.0
  const bf16x8 onef = {one_bf, one_bf, one_bf, one_bf,
                       one_bf, one_bf, one_bf, one_bf};

  bf16x8 kfA[4], kfB[4];
  #pragma unroll
  for (int jt = 0; jt < 4; jt++)
    kfA[jt] = *(const bf16x8*)(kb + (jbase + jt * 16) * 8 + koff);

  STAGE(0, kfA, kfB, jbase + 256);
  for (int it2 = 0; it2 < 8; ++it2) {
    BODY(2 * it2 + 1, kfB, kfA);
    BODY(2 * it2 + 2, kfA, kfB);
  }
  BODY(17, kfB, kfA);

  // epilogue: PV(17) + l(17)
  {
    const int jp = jbase + (17 << 8);
    unsigned short* pr = pb + 2304;   // buffer 17&1
    #pragma unroll
    for (int s = 0; s < 2; s++) {
      bf16x8 pf0 = *(const bf16x8*)(&pr[(s * 16 + i16) * 72 + (((2 * quad) ^ sw) << 2)]);
      bf16x8 pf1 = *(const bf16x8*)(&pr[(s * 16 + i16) * 72 + (((8 + 2 * quad) ^ sw) << 2)]);
      #pragma unroll
      for (int ct = 0; ct < 4; ct++) {
        bf16x8 vf0 = *(const bf16x8*)(vb + ct * 16 * NTOK + voff + jp);
        bf16x8 vf1 = *(const bf16x8*)(vb + ct * 16 * NTOK + voff + jp + 32);
        acc[s][ct] = __builtin_amdgcn_mfma_f32_16x16x32_bf16(vf0, pf0, acc[s][ct], 0, 0, 0);
        acc[s][ct] = __builtin_amdgcn_mfma_f32_16x16x32_bf16(vf1, pf1, acc[s][ct], 0, 0, 0);
      }
      accl[s] = __builtin_amdgcn_mfma_f32_16x16x32_bf16(onef, pf0, accl[s], 0, 0, 0);
      accl[s] = __builtin_amdgcn_mfma_f32_16x16x32_bf16(onef, pf1, accl[s], 0, 0, 0);
    }
  }

  // l per row: every C/D row of ones·P^T holds the same row-sum -> reg 0,
  // no cross-lane reduction needed.
  if (quad == 0) { l_s[w][i16] = accl[0][0]; l_s[w][16 + i16] = accl[1][0]; }

  __syncthreads();                 // all P-tile reads done -> overlay obuf
  float* obuf = (float*)p_lds;     // [4][64][33] = 33792 B <= 36864 B
  #pragma unroll
  for (int s = 0; s < 2; s++)
    #pragma unroll
    for (int ct = 0; ct < 4; ct++)
      #pragma unroll
      for (int r = 0; r < 4; r++)
        obuf[w * 2112 + (ct * 16 + quad * 4 + r) * 33 + s * 16 + i16] = acc[s][ct][r];
  __syncthreads();

  float* ob = opart + (size_t)bid * 2048;
  #pragma unroll
  for (int e0 = 0; e0 < 8; e0++) {
    int e = tid + e0 * 256, c = e >> 5, r = e & 31;
    ob[e] = obuf[c * 33 + r] + obuf[2112 + c * 33 + r]
          + obuf[4224 + c * 33 + r] + obuf[6336 + c * 33 + r];
  }
  if (tid < 32)
    lpart[(size_t)bid * 32 + tid] =
        l_s[0][tid] + l_s[1][tid] + l_s[2][tid] + l_s[3][tid];
}

// ---------------------------------------------------------------------------
// Kernel 3: merge the 2 j-half partials + epilogue: y = gs*O/L + x
// ---------------------------------------------------------------------------
__global__ __launch_bounds__(256) void reduce_ep(
    const float* __restrict__ x,
    const float* __restrict__ opart, const float* __restrict__ lpart,
    const float* __restrict__ gamma_p, const float* __restrict__ dyn_p,
    float* __restrict__ y)
{
  const int bid = blockIdx.x;            // b*288 + rt
  const int b = bid / 288, rt = bid % 288;
  const int tid = threadIdx.x;
  const float gs = gamma_p[0] * dyn_p[0];
  const float* o0 = opart + (size_t)(bid * 2) * 2048;
  const float* o1 = o0 + 2048;
  const float* l0 = lpart + (size_t)(bid * 2) * 32;
  const float* l1 = l0 + 32;
  #pragma unroll
  for (int e0 = 0; e0 < 8; e0++) {
    int e = tid + e0 * 256, c = e >> 5, r = e & 31;
    float L = l0[r] + l1[r];
    float O = o0[e] + o1[e];
    size_t a = (size_t)(b * 64 + c) * NTOK + rt * 32 + r;
    y[a] = gs * O / L + x[a];
  }
}

// ---------------------------------------------------------------------------
extern "C" void kernel_launch(void* const* d_in, const int* in_sizes, int n_in,
                              void* d_out, int out_size, void* d_ws, size_t ws_size,
                              hipStream_t stream) {
  const float* x     = (const float*)d_in[0];
  const float* Wq    = (const float*)d_in[1];
  const float* bq    = (const float*)d_in[2];
  const float* Wk    = (const float*)d_in[3];
  const float* bk    = (const float*)d_in[4];
  const float* Wv    = (const float*)d_in[5];
  const float* bv    = (const float*)d_in[6];
  const float* gamma = (const float*)d_in[7];
  const float* dyn   = (const float*)d_in[8];
  float* y = (float*)d_out;

  // workspace layout (bf16 then f32, 16B-aligned boundaries)
  unsigned short* qg = (unsigned short*)d_ws;              // B*N*8
  unsigned short* kg = qg + (size_t)NBAT * NTOK * 8;       // B*N*8
  unsigned short* vg = kg + (size_t)NBAT * NTOK * 8;       // B*64*N
  float* opart = (float*)(vg + (size_t)NBAT * 64 * NTOK);  // 1152*2048
  float* lpart = opart + (size_t)1152 * 2048;              // 1152*32

  qkv_proj<<<NBAT * 144 * 10, 256, 0, stream>>>(x, Wq, bq, Wk, bk, Wv, bv, qg, kg, vg);
  flash_partial<<<NBAT * 288 * 2, 256, 0, stream>>>(qg, kg, vg, opart, lpart);
  reduce_ep<<<NBAT * 288, 256, 0, stream>>>(x, opart, lpart, gamma, dyn, y);
}

// Round 10
// 186.957 us; speedup vs baseline: 1.6189x; 1.0082x over previous
//
#include <hip/hip_runtime.h>

// Problem constants (B=2, C=64, C8=8, H=W=96 -> N=9216)
#define NTOK  9216
#define NBAT  2

typedef __attribute__((ext_vector_type(8))) short bf16x8;
typedef __attribute__((ext_vector_type(4))) float f32x4;

#if __has_builtin(__builtin_amdgcn_exp2f)
#define EXP2(x) __builtin_amdgcn_exp2f(x)
#else
#define EXP2(x) exp2f(x)
#endif
#define L2E 1.4426950408889634f

__device__ __forceinline__ unsigned short f2bf(float x) {
  unsigned int u = __builtin_bit_cast(unsigned int, x);
  u += 0x7fffu + ((u >> 16) & 1u);   // RNE
  return (unsigned short)(u >> 16);
}

// pack two non-negative floats to bf16x2 (round-half-up via +0x8000, v_perm)
__device__ __forceinline__ unsigned int pack_bf2(float lo, float hi) {
  unsigned int ulo = __builtin_bit_cast(unsigned int, lo) + 0x8000u;
  unsigned int uhi = __builtin_bit_cast(unsigned int, hi) + 0x8000u;
  return __builtin_amdgcn_perm(uhi, ulo, 0x07060302u);
}

// ---------------------------------------------------------------------------
// Kernel 1: QKV projections -> bf16 (R7/R8 wl-LDS version — best measured
// side-car). qg = (q+bq)*log2e; kg[b][n][8].
// V is written TILED: vt[b][n/64][c][n%64] so flash's V-fragment loads are
// contiguous 1KB blocks (ideal coalescing) instead of 16 lines at 18KB
// stride. W rows staged in LDS, copied to VGPRs once; inner loop has no
// scalar-memory ops.
// ---------------------------------------------------------------------------
__global__ __launch_bounds__(256) void qkv_proj(
    const float* __restrict__ x,
    const float* __restrict__ Wq, const float* __restrict__ bq,
    const float* __restrict__ Wk, const float* __restrict__ bk,
    const float* __restrict__ Wv, const float* __restrict__ bv,
    unsigned short* __restrict__ qg, unsigned short* __restrict__ kg,
    unsigned short* __restrict__ vt)
{
  __shared__ __align__(16) float xl[64 * 68];
  __shared__ __align__(16) float wl[16 * 64];
  __shared__ float bl[16];
  const int bid = blockIdx.x;
  const int rg  = bid % 5;
  const int t2  = bid / 5;
  const int nt  = t2 % 144;
  const int b   = t2 / 144;
  const int t   = threadIdx.x;
  const int lane = t & 63;
  const int n0  = nt * 64;

  // stage this block's 16 W rows (rg*16 .. rg*16+15) + biases
  {
    int grow = rg * 16 + (t >> 4);
    const float* src; int lr;
    if (grow < 8)       { src = Wq; lr = grow; }
    else if (grow < 16) { src = Wk; lr = grow - 8; }
    else                { src = Wv; lr = grow - 16; }
    *(float4*)&wl[(t >> 4) * 64 + (t & 15) * 4] =
        *(const float4*)(src + lr * 64 + (t & 15) * 4);
    if (t < 16) {
      int gr = rg * 16 + t;
      bl[t] = gr < 8 ? bq[gr] : (gr < 16 ? bk[gr - 8] : bv[gr - 16]);
    }
  }
  // stage x tile [64 cin][64 n]
  #pragma unroll
  for (int kk = 0; kk < 4; kk++) {
    int p = t + kk * 256;
    int c = p >> 4, n4 = (p & 15) << 2;
    *(float4*)(&xl[c * 68 + n4]) =
        *(const float4*)(x + (size_t)(b * 64 + c) * NTOK + n0 + n4);
  }
  __syncthreads();

  const int g  = __builtin_amdgcn_readfirstlane(t >> 6);  // wave id 0..3
  const int r0 = rg * 16 + g * 4;                         // rows r0..r0+3

  // W rows LDS -> VGPRs once (uniform-address broadcast b128 reads)
  float4 wr[4][16];
  #pragma unroll
  for (int rr = 0; rr < 4; rr++)
    #pragma unroll
    for (int q4 = 0; q4 < 16; q4++)
      wr[rr][q4] = *(const float4*)&wl[(g * 4 + rr) * 64 + q4 * 4];

  float a0 = 0.f, a1 = 0.f, a2 = 0.f, a3 = 0.f;
  #pragma unroll
  for (int c4 = 0; c4 < 16; c4++) {
    float x0 = xl[(c4 * 4 + 0) * 68 + lane];
    float x1 = xl[(c4 * 4 + 1) * 68 + lane];
    float x2 = xl[(c4 * 4 + 2) * 68 + lane];
    float x3 = xl[(c4 * 4 + 3) * 68 + lane];
    a0 = fmaf(wr[0][c4].x, x0, a0); a0 = fmaf(wr[0][c4].y, x1, a0);
    a0 = fmaf(wr[0][c4].z, x2, a0); a0 = fmaf(wr[0][c4].w, x3, a0);
    a1 = fmaf(wr[1][c4].x, x0, a1); a1 = fmaf(wr[1][c4].y, x1, a1);
    a1 = fmaf(wr[1][c4].z, x2, a1); a1 = fmaf(wr[1][c4].w, x3, a1);
    a2 = fmaf(wr[2][c4].x, x0, a2); a2 = fmaf(wr[2][c4].y, x1, a2);
    a2 = fmaf(wr[2][c4].z, x2, a2); a2 = fmaf(wr[2][c4].w, x3, a2);
    a3 = fmaf(wr[3][c4].x, x0, a3); a3 = fmaf(wr[3][c4].y, x1, a3);
    a3 = fmaf(wr[3][c4].z, x2, a3); a3 = fmaf(wr[3][c4].w, x3, a3);
  }
  a0 += bl[g * 4 + 0]; a1 += bl[g * 4 + 1];
  a2 += bl[g * 4 + 2]; a3 += bl[g * 4 + 3];
  if (r0 < 8) { a0 *= L2E; a1 *= L2E; a2 *= L2E; a3 *= L2E; }  // wave-uniform

  const int n = n0 + lane;
  if (r0 < 16) {
    ushort4 o;
    o.x = f2bf(a0); o.y = f2bf(a1); o.z = f2bf(a2); o.w = f2bf(a3);
    int lr0 = (r0 < 8) ? r0 : r0 - 8;
    unsigned short* dst = (r0 < 8) ? qg : kg;
    *(ushort4*)(dst + ((size_t)b * NTOK + n) * 8 + lr0) = o;
  } else {
    int lr0 = r0 - 16;
    // tiled: vt[((b*144 + nt)*64 + c)*64 + lane]
    unsigned short* vrow = vt + (((size_t)b * 144 + nt) * 64 + lr0) * 64 + lane;
    vrow[0]   = f2bf(a0);
    vrow[64]  = f2bf(a1);
    vrow[128] = f2bf(a2);
    vrow[192] = f2bf(a3);
  }
}

// ---------------------------------------------------------------------------
// Kernel 2: flash partial (R9 core: 32 rows/wave, split-j, alternating K frag
// banks, pipelined dbuf P round-trip, granule-XOR swizzle, l on the MFMA
// pipe). V loads now hit the TILED layout: each fragment = one contiguous
// 1KB block per wave (lane stride 16B).
// ---------------------------------------------------------------------------

#define STAGE(IT_, KFU_, KFP_, JNEXT_)                                        \
  {                                                                           \
    unsigned short* pwb = pb + ((IT_) & 1) * 2304;                            \
    f32x4 st[4];                                                              \
    _Pragma("unroll")                                                         \
    for (int jt = 0; jt < 4; jt++)                                            \
      st[jt] = __builtin_amdgcn_mfma_f32_16x16x32_bf16(KFU_[jt], qf[0], z4, 0, 0, 0); \
    _Pragma("unroll")                                                         \
    for (int jt = 0; jt < 4; jt++)                                            \
      KFP_[jt] = *(const bf16x8*)(kb + ((JNEXT_) + jt * 16) * 8 + koff);      \
    _Pragma("unroll")                                                         \
    for (int jt = 0; jt < 4; jt++) {                                          \
      float p0 = EXP2(st[jt][0]);                                             \
      float p1 = EXP2(st[jt][1]);                                             \
      float p2 = EXP2(st[jt][2]);                                             \
      float p3 = EXP2(st[jt][3]);                                             \
      *(uint2*)(&pwb[i16 * 72 + (((jt * 4 + quad) ^ sw) << 2)]) =             \
          make_uint2(pack_bf2(p0, p1), pack_bf2(p2, p3));                     \
    }                                                                         \
    _Pragma("unroll")                                                         \
    for (int jt = 0; jt < 4; jt++)                                            \
      st[jt] = __builtin_amdgcn_mfma_f32_16x16x32_bf16(KFU_[jt], qf[1], z4, 0, 0, 0); \
    _Pragma("unroll")                                                         \
    for (int jt = 0; jt < 4; jt++) {                                          \
      float p0 = EXP2(st[jt][0]);                                             \
      float p1 = EXP2(st[jt][1]);                                             \
      float p2 = EXP2(st[jt][2]);                                             \
      float p3 = EXP2(st[jt][3]);                                             \
      *(uint2*)(&pwb[(16 + i16) * 72 + (((jt * 4 + quad) ^ sw) << 2)]) =      \
          make_uint2(pack_bf2(p0, p1), pack_bf2(p2, p3));                     \
    }                                                                         \
  }

#define BODY(IT_, KFU_, KFP_)                                                 \
  {                                                                           \
    const int jp = jbase + (((IT_) - 1) << 8);                                \
    const int jn = ((IT_) == 17) ? jbase : jbase + (((IT_) + 1) << 8);        \
    unsigned short* pr = pb + (((IT_) - 1) & 1) * 2304;                       \
    bf16x8 pf[2][2];                                                          \
    _Pragma("unroll")                                                         \
    for (int s = 0; s < 2; s++) {                                             \
      pf[s][0] = *(const bf16x8*)(&pr[(s * 16 + i16) * 72 + (((2 * quad) ^ sw) << 2)]); \
      pf[s][1] = *(const bf16x8*)(&pr[(s * 16 + i16) * 72 + (((8 + 2 * quad) ^ sw) << 2)]); \
    }                                                                         \
    const unsigned short* vtp = vb + (size_t)jp * 64 + voff;                  \
    bf16x8 vf0[4];                                                            \
    _Pragma("unroll")                                                         \
    for (int ct = 0; ct < 4; ct++)                                            \
      vf0[ct] = *(const bf16x8*)(vtp + ct * 1024);                            \
    STAGE(IT_, KFU_, KFP_, jn);                                               \
    bf16x8 vf1[4];                                                            \
    _Pragma("unroll")                                                         \
    for (int ct = 0; ct < 4; ct++)                                            \
      vf1[ct] = *(const bf16x8*)(vtp + ct * 1024 + 32);                       \
    _Pragma("unroll")                                                         \
    for (int s = 0; s < 2; s++) {                                             \
      _Pragma("unroll")                                                       \
      for (int ct = 0; ct < 4; ct++)                                          \
        acc[s][ct] = __builtin_amdgcn_mfma_f32_16x16x32_bf16(vf0[ct], pf[s][0], acc[s][ct], 0, 0, 0); \
      accl[s] = __builtin_amdgcn_mfma_f32_16x16x32_bf16(onef, pf[s][0], accl[s], 0, 0, 0); \
    }                                                                         \
    _Pragma("unroll")                                                         \
    for (int s = 0; s < 2; s++) {                                             \
      _Pragma("unroll")                                                       \
      for (int ct = 0; ct < 4; ct++)                                          \
        acc[s][ct] = __builtin_amdgcn_mfma_f32_16x16x32_bf16(vf1[ct], pf[s][1], acc[s][ct], 0, 0, 0); \
      accl[s] = __builtin_amdgcn_mfma_f32_16x16x32_bf16(onef, pf[s][1], accl[s], 0, 0, 0); \
    }                                                                         \
  }

__global__ __launch_bounds__(256, 4) void flash_partial(
    const unsigned short* __restrict__ qg,
    const unsigned short* __restrict__ kg,
    const unsigned short* __restrict__ vt,
    float* __restrict__ opart, float* __restrict__ lpart)
{
  __shared__ __align__(16) unsigned short p_lds[4 * 2 * 32 * 72]; // 36864 B
  __shared__ float l_s[4][32];

  const int bid  = blockIdx.x;
  const int jh   = bid & 1;
  const int rt   = (bid >> 1) % 288;
  const int b    = (bid >> 1) / 288;
  const int tid  = threadIdx.x;
  const int w    = tid >> 6;
  const int lane = tid & 63;
  const int i16  = lane & 15;
  const int quad = lane >> 4;
  const int jbase = jh * 4608 + (w << 6);
  const int sw   = (i16 & 3) << 2;          // P-tile granule-XOR swizzle

  unsigned short* pb = &p_lds[w * 4608];

  // tiled V base: vt[b][j/64][c][j%64]; fragment offset = j*64 + c*64... :
  //   elem addr = (b*144 + j0/64)*4096 + ct*1024 + i16*64 + quad*8 (+32)
  //             = vb + j0*64 + ct*1024 + voff
  const unsigned short* __restrict__ vb = vt + (size_t)b * 144 * 4096;
  const unsigned short* __restrict__ kb = kg + (size_t)b * NTOK * 8;
  const int koff = i16 * 8;
  const int voff = i16 * 64 + quad * 8;

  bf16x8 qf[2] = {};
  if (quad == 0) {
    qf[0] = *(const bf16x8*)(qg + ((size_t)b * NTOK + rt * 32 + i16) * 8);
    qf[1] = *(const bf16x8*)(qg + ((size_t)b * NTOK + rt * 32 + 16 + i16) * 8);
  }

  f32x4 acc[2][4], accl[2];
  #pragma unroll
  for (int s = 0; s < 2; s++) {
    #pragma unroll
    for (int ct = 0; ct < 4; ct++) acc[s][ct] = (f32x4){0.f, 0.f, 0.f, 0.f};
    accl[s] = (f32x4){0.f, 0.f, 0.f, 0.f};
  }
  const f32x4 z4 = {0.f, 0.f, 0.f, 0.f};
  const short one_bf = (short)0x3F80;      // bf16 1.0
  const bf16x8 onef = {one_bf, one_bf, one_bf, one_bf,
                       one_bf, one_bf, one_bf, one_bf};

  bf16x8 kfA[4], kfB[4];
  #pragma unroll
  for (int jt = 0; jt < 4; jt++)
    kfA[jt] = *(const bf16x8*)(kb + (jbase + jt * 16) * 8 + koff);

  STAGE(0, kfA, kfB, jbase + 256);
  for (int it2 = 0; it2 < 8; ++it2) {
    BODY(2 * it2 + 1, kfB, kfA);
    BODY(2 * it2 + 2, kfA, kfB);
  }
  BODY(17, kfB, kfA);

  // epilogue: PV(17) + l(17)
  {
    const int jp = jbase + (17 << 8);
    unsigned short* pr = pb + 2304;   // buffer 17&1
    const unsigned short* vtp = vb + (size_t)jp * 64 + voff;
    #pragma unroll
    for (int s = 0; s < 2; s++) {
      bf16x8 pf0 = *(const bf16x8*)(&pr[(s * 16 + i16) * 72 + (((2 * quad) ^ sw) << 2)]);
      bf16x8 pf1 = *(const bf16x8*)(&pr[(s * 16 + i16) * 72 + (((8 + 2 * quad) ^ sw) << 2)]);
      #pragma unroll
      for (int ct = 0; ct < 4; ct++) {
        bf16x8 vf0 = *(const bf16x8*)(vtp + ct * 1024);
        bf16x8 vf1 = *(const bf16x8*)(vtp + ct * 1024 + 32);
        acc[s][ct] = __builtin_amdgcn_mfma_f32_16x16x32_bf16(vf0, pf0, acc[s][ct], 0, 0, 0);
        acc[s][ct] = __builtin_amdgcn_mfma_f32_16x16x32_bf16(vf1, pf1, acc[s][ct], 0, 0, 0);
      }
      accl[s] = __builtin_amdgcn_mfma_f32_16x16x32_bf16(onef, pf0, accl[s], 0, 0, 0);
      accl[s] = __builtin_amdgcn_mfma_f32_16x16x32_bf16(onef, pf1, accl[s], 0, 0, 0);
    }
  }

  // l per row: every C/D row of ones·P^T holds the same row-sum -> reg 0
  if (quad == 0) { l_s[w][i16] = accl[0][0]; l_s[w][16 + i16] = accl[1][0]; }

  __syncthreads();                 // all P-tile reads done -> overlay obuf
  float* obuf = (float*)p_lds;     // [4][64][33] = 33792 B <= 36864 B
  #pragma unroll
  for (int s = 0; s < 2; s++)
    #pragma unroll
    for (int ct = 0; ct < 4; ct++)
      #pragma unroll
      for (int r = 0; r < 4; r++)
        obuf[w * 2112 + (ct * 16 + quad * 4 + r) * 33 + s * 16 + i16] = acc[s][ct][r];
  __syncthreads();

  float* ob = opart + (size_t)bid * 2048;
  #pragma unroll
  for (int e0 = 0; e0 < 8; e0++) {
    int e = tid + e0 * 256, c = e >> 5, r = e & 31;
    ob[e] = obuf[c * 33 + r] + obuf[2112 + c * 33 + r]
          + obuf[4224 + c * 33 + r] + obuf[6336 + c * 33 + r];
  }
  if (tid < 32)
    lpart[(size_t)bid * 32 + tid] =
        l_s[0][tid] + l_s[1][tid] + l_s[2][tid] + l_s[3][tid];
}

// ---------------------------------------------------------------------------
// Kernel 3: merge the 2 j-half partials + epilogue: y = gs*O/L + x
// ---------------------------------------------------------------------------
__global__ __launch_bounds__(256) void reduce_ep(
    const float* __restrict__ x,
    const float* __restrict__ opart, const float* __restrict__ lpart,
    const float* __restrict__ gamma_p, const float* __restrict__ dyn_p,
    float* __restrict__ y)
{
  const int bid = blockIdx.x;            // b*288 + rt
  const int b = bid / 288, rt = bid % 288;
  const int tid = threadIdx.x;
  const float gs = gamma_p[0] * dyn_p[0];
  const float* o0 = opart + (size_t)(bid * 2) * 2048;
  const float* o1 = o0 + 2048;
  const float* l0 = lpart + (size_t)(bid * 2) * 32;
  const float* l1 = l0 + 32;
  #pragma unroll
  for (int e0 = 0; e0 < 8; e0++) {
    int e = tid + e0 * 256, c = e >> 5, r = e & 31;
    float L = l0[r] + l1[r];
    float O = o0[e] + o1[e];
    size_t a = (size_t)(b * 64 + c) * NTOK + rt * 32 + r;
    y[a] = gs * O / L + x[a];
  }
}

// ---------------------------------------------------------------------------
extern "C" void kernel_launch(void* const* d_in, const int* in_sizes, int n_in,
                              void* d_out, int out_size, void* d_ws, size_t ws_size,
                              hipStream_t stream) {
  const float* x     = (const float*)d_in[0];
  const float* Wq    = (const float*)d_in[1];
  const float* bq    = (const float*)d_in[2];
  const float* Wk    = (const float*)d_in[3];
  const float* bk    = (const float*)d_in[4];
  const float* Wv    = (const float*)d_in[5];
  const float* bv    = (const float*)d_in[6];
  const float* gamma = (const float*)d_in[7];
  const float* dyn   = (const float*)d_in[8];
  float* y = (float*)d_out;

  // workspace layout (bf16 then f32, 16B-aligned boundaries)
  unsigned short* qg = (unsigned short*)d_ws;              // B*N*8
  unsigned short* kg = qg + (size_t)NBAT * NTOK * 8;       // B*N*8
  unsigned short* vt = kg + (size_t)NBAT * NTOK * 8;       // B*144*64*64
  float* opart = (float*)(vt + (size_t)NBAT * 144 * 4096); // 1152*2048
  float* lpart = opart + (size_t)1152 * 2048;              // 1152*32

  qkv_proj<<<NBAT * 144 * 5, 256, 0, stream>>>(x, Wq, bq, Wk, bk, Wv, bv, qg, kg, vt);
  flash_partial<<<NBAT * 288 * 2, 256, 0, stream>>>(qg, kg, vt, opart, lpart);
  reduce_ep<<<NBAT * 288, 256, 0, stream>>>(x, opart, lpart, gamma, dyn, y);
}

// Round 11
// 185.555 us; speedup vs baseline: 1.6311x; 1.0076x over previous
//
#include <hip/hip_runtime.h>

// Problem constants (B=2, C=64, C8=8, H=W=96 -> N=9216)
#define NTOK  9216
#define NBAT  2

typedef __attribute__((ext_vector_type(8))) short bf16x8;
typedef __attribute__((ext_vector_type(4))) float f32x4;
typedef __attribute__((ext_vector_type(2))) short bf16x2;

#if __has_builtin(__builtin_amdgcn_exp2f)
#define EXP2(x) __builtin_amdgcn_exp2f(x)
#else
#define EXP2(x) exp2f(x)
#endif
#define L2E 1.4426950408889634f

__device__ __forceinline__ unsigned short f2bf(float x) {
  unsigned int u = __builtin_bit_cast(unsigned int, x);
  u += 0x7fffu + ((u >> 16) & 1u);   // RNE
  return (unsigned short)(u >> 16);
}

// pack two floats -> bf16x2 in one v_cvt_pk_bf16_f32 when available,
// else 3-op round-half-up + v_perm fallback.
#if __has_builtin(__builtin_amdgcn_cvt_pk_bf16_f32)
__device__ __forceinline__ unsigned int pack_bf2(float lo, float hi) {
  bf16x2 r = __builtin_amdgcn_cvt_pk_bf16_f32(lo, hi);
  return __builtin_bit_cast(unsigned int, r);
}
#else
__device__ __forceinline__ unsigned int pack_bf2(float lo, float hi) {
  unsigned int ulo = __builtin_bit_cast(unsigned int, lo) + 0x8000u;
  unsigned int uhi = __builtin_bit_cast(unsigned int, hi) + 0x8000u;
  return __builtin_amdgcn_perm(uhi, ulo, 0x07060302u);
}
#endif

// ---------------------------------------------------------------------------
// Kernel 1: QKV projections -> bf16 (R8 wl-LDS version — best measured
// side-car). qg = (q+bq)*log2e; kg[b][n][8]; vg[b][c][n] (c-major).
// W rows staged in LDS, copied to VGPRs once; inner loop has no scalar-mem.
// ---------------------------------------------------------------------------
__global__ __launch_bounds__(256) void qkv_proj(
    const float* __restrict__ x,
    const float* __restrict__ Wq, const float* __restrict__ bq,
    const float* __restrict__ Wk, const float* __restrict__ bk,
    const float* __restrict__ Wv, const float* __restrict__ bv,
    unsigned short* __restrict__ qg, unsigned short* __restrict__ kg,
    unsigned short* __restrict__ vg)
{
  __shared__ __align__(16) float xl[64 * 68];
  __shared__ __align__(16) float wl[16 * 64];
  __shared__ float bl[16];
  const int bid = blockIdx.x;
  const int rg  = bid % 5;
  const int t2  = bid / 5;
  const int nt  = t2 % 144;
  const int b   = t2 / 144;
  const int t   = threadIdx.x;
  const int lane = t & 63;
  const int n0  = nt * 64;

  // stage this block's 16 W rows (rg*16 .. rg*16+15) + biases
  {
    int grow = rg * 16 + (t >> 4);
    const float* src; int lr;
    if (grow < 8)       { src = Wq; lr = grow; }
    else if (grow < 16) { src = Wk; lr = grow - 8; }
    else                { src = Wv; lr = grow - 16; }
    *(float4*)&wl[(t >> 4) * 64 + (t & 15) * 4] =
        *(const float4*)(src + lr * 64 + (t & 15) * 4);
    if (t < 16) {
      int gr = rg * 16 + t;
      bl[t] = gr < 8 ? bq[gr] : (gr < 16 ? bk[gr - 8] : bv[gr - 16]);
    }
  }
  // stage x tile [64 cin][64 n]
  #pragma unroll
  for (int kk = 0; kk < 4; kk++) {
    int p = t + kk * 256;
    int c = p >> 4, n4 = (p & 15) << 2;
    *(float4*)(&xl[c * 68 + n4]) =
        *(const float4*)(x + (size_t)(b * 64 + c) * NTOK + n0 + n4);
  }
  __syncthreads();

  const int g  = __builtin_amdgcn_readfirstlane(t >> 6);  // wave id 0..3
  const int r0 = rg * 16 + g * 4;                         // rows r0..r0+3

  // W rows LDS -> VGPRs once (uniform-address broadcast b128 reads)
  float4 wr[4][16];
  #pragma unroll
  for (int rr = 0; rr < 4; rr++)
    #pragma unroll
    for (int q4 = 0; q4 < 16; q4++)
      wr[rr][q4] = *(const float4*)&wl[(g * 4 + rr) * 64 + q4 * 4];

  float a0 = 0.f, a1 = 0.f, a2 = 0.f, a3 = 0.f;
  #pragma unroll
  for (int c4 = 0; c4 < 16; c4++) {
    float x0 = xl[(c4 * 4 + 0) * 68 + lane];
    float x1 = xl[(c4 * 4 + 1) * 68 + lane];
    float x2 = xl[(c4 * 4 + 2) * 68 + lane];
    float x3 = xl[(c4 * 4 + 3) * 68 + lane];
    a0 = fmaf(wr[0][c4].x, x0, a0); a0 = fmaf(wr[0][c4].y, x1, a0);
    a0 = fmaf(wr[0][c4].z, x2, a0); a0 = fmaf(wr[0][c4].w, x3, a0);
    a1 = fmaf(wr[1][c4].x, x0, a1); a1 = fmaf(wr[1][c4].y, x1, a1);
    a1 = fmaf(wr[1][c4].z, x2, a1); a1 = fmaf(wr[1][c4].w, x3, a1);
    a2 = fmaf(wr[2][c4].x, x0, a2); a2 = fmaf(wr[2][c4].y, x1, a2);
    a2 = fmaf(wr[2][c4].z, x2, a2); a2 = fmaf(wr[2][c4].w, x3, a2);
    a3 = fmaf(wr[3][c4].x, x0, a3); a3 = fmaf(wr[3][c4].y, x1, a3);
    a3 = fmaf(wr[3][c4].z, x2, a3); a3 = fmaf(wr[3][c4].w, x3, a3);
  }
  a0 += bl[g * 4 + 0]; a1 += bl[g * 4 + 1];
  a2 += bl[g * 4 + 2]; a3 += bl[g * 4 + 3];
  if (r0 < 8) { a0 *= L2E; a1 *= L2E; a2 *= L2E; a3 *= L2E; }  // wave-uniform

  const int n = n0 + lane;
  if (r0 < 16) {
    ushort4 o;
    o.x = f2bf(a0); o.y = f2bf(a1); o.z = f2bf(a2); o.w = f2bf(a3);
    int lr0 = (r0 < 8) ? r0 : r0 - 8;
    unsigned short* dst = (r0 < 8) ? qg : kg;
    *(ushort4*)(dst + ((size_t)b * NTOK + n) * 8 + lr0) = o;
  } else {
    int lr0 = r0 - 16;
    vg[(size_t)(b * 64 + lr0)     * NTOK + n] = f2bf(a0);
    vg[(size_t)(b * 64 + lr0 + 1) * NTOK + n] = f2bf(a1);
    vg[(size_t)(b * 64 + lr0 + 2) * NTOK + n] = f2bf(a2);
    vg[(size_t)(b * 64 + lr0 + 3) * NTOK + n] = f2bf(a3);
  }
}

// ---------------------------------------------------------------------------
// Kernel 2: flash partial (R9 core, best measured: 32 rows/wave, split-j,
// alternating K frag banks, pipelined dbuf P round-trip, granule-XOR
// swizzle, l on the MFMA pipe, non-tiled V).
// ---------------------------------------------------------------------------

#define STAGE(IT_, KFU_, KFP_, JNEXT_)                                        \
  {                                                                           \
    unsigned short* pwb = pb + ((IT_) & 1) * 2304;                            \
    f32x4 st[4];                                                              \
    _Pragma("unroll")                                                         \
    for (int jt = 0; jt < 4; jt++)                                            \
      st[jt] = __builtin_amdgcn_mfma_f32_16x16x32_bf16(KFU_[jt], qf[0], z4, 0, 0, 0); \
    _Pragma("unroll")                                                         \
    for (int jt = 0; jt < 4; jt++)                                            \
      KFP_[jt] = *(const bf16x8*)(kb + ((JNEXT_) + jt * 16) * 8 + koff);      \
    _Pragma("unroll")                                                         \
    for (int jt = 0; jt < 4; jt++) {                                          \
      float p0 = EXP2(st[jt][0]);                                             \
      float p1 = EXP2(st[jt][1]);                                             \
      float p2 = EXP2(st[jt][2]);                                             \
      float p3 = EXP2(st[jt][3]);                                             \
      *(uint2*)(&pwb[i16 * 72 + (((jt * 4 + quad) ^ sw) << 2)]) =             \
          make_uint2(pack_bf2(p0, p1), pack_bf2(p2, p3));                     \
    }                                                                         \
    _Pragma("unroll")                                                         \
    for (int jt = 0; jt < 4; jt++)                                            \
      st[jt] = __builtin_amdgcn_mfma_f32_16x16x32_bf16(KFU_[jt], qf[1], z4, 0, 0, 0); \
    _Pragma("unroll")                                                         \
    for (int jt = 0; jt < 4; jt++) {                                          \
      float p0 = EXP2(st[jt][0]);                                             \
      float p1 = EXP2(st[jt][1]);                                             \
      float p2 = EXP2(st[jt][2]);                                             \
      float p3 = EXP2(st[jt][3]);                                             \
      *(uint2*)(&pwb[(16 + i16) * 72 + (((jt * 4 + quad) ^ sw) << 2)]) =      \
          make_uint2(pack_bf2(p0, p1), pack_bf2(p2, p3));                     \
    }                                                                         \
  }

#define BODY(IT_, KFU_, KFP_)                                                 \
  {                                                                           \
    const int jp = jbase + (((IT_) - 1) << 8);                                \
    const int jn = ((IT_) == 17) ? jbase : jbase + (((IT_) + 1) << 8);        \
    unsigned short* pr = pb + (((IT_) - 1) & 1) * 2304;                       \
    bf16x8 pf[2][2];                                                          \
    _Pragma("unroll")                                                         \
    for (int s = 0; s < 2; s++) {                                             \
      pf[s][0] = *(const bf16x8*)(&pr[(s * 16 + i16) * 72 + (((2 * quad) ^ sw) << 2)]); \
      pf[s][1] = *(const bf16x8*)(&pr[(s * 16 + i16) * 72 + (((8 + 2 * quad) ^ sw) << 2)]); \
    }                                                                         \
    bf16x8 vf0[4];                                                            \
    _Pragma("unroll")                                                         \
    for (int ct = 0; ct < 4; ct++)                                            \
      vf0[ct] = *(const bf16x8*)(vb + ct * 16 * NTOK + voff + jp);            \
    STAGE(IT_, KFU_, KFP_, jn);                                               \
    bf16x8 vf1[4];                                                            \
    _Pragma("unroll")                                                         \
    for (int ct = 0; ct < 4; ct++)                                            \
      vf1[ct] = *(const bf16x8*)(vb + ct * 16 * NTOK + voff + jp + 32);       \
    _Pragma("unroll")                                                         \
    for (int s = 0; s < 2; s++) {                                             \
      _Pragma("unroll")                                                       \
      for (int ct = 0; ct < 4; ct++)                                          \
        acc[s][ct] = __builtin_amdgcn_mfma_f32_16x16x32_bf16(vf0[ct], pf[s][0], acc[s][ct], 0, 0, 0); \
      accl[s] = __builtin_amdgcn_mfma_f32_16x16x32_bf16(onef, pf[s][0], accl[s], 0, 0, 0); \
    }                                                                         \
    _Pragma("unroll")                                                         \
    for (int s = 0; s < 2; s++) {                                             \
      _Pragma("unroll")                                                       \
      for (int ct = 0; ct < 4; ct++)                                          \
        acc[s][ct] = __builtin_amdgcn_mfma_f32_16x16x32_bf16(vf1[ct], pf[s][1], acc[s][ct], 0, 0, 0); \
      accl[s] = __builtin_amdgcn_mfma_f32_16x16x32_bf16(onef, pf[s][1], accl[s], 0, 0, 0); \
    }                                                                         \
  }

__global__ __launch_bounds__(256, 4) void flash_partial(
    const unsigned short* __restrict__ qg,
    const unsigned short* __restrict__ kg,
    const unsigned short* __restrict__ vg,
    float* __restrict__ opart, float* __restrict__ lpart)
{
  __shared__ __align__(16) unsigned short p_lds[4 * 2 * 32 * 72]; // 36864 B
  __shared__ float l_s[4][32];

  const int bid  = blockIdx.x;
  const int jh   = bid & 1;
  const int rt   = (bid >> 1) % 288;
  const int b    = (bid >> 1) / 288;
  const int tid  = threadIdx.x;
  const int w    = tid >> 6;
  const int lane = tid & 63;
  const int i16  = lane & 15;
  const int quad = lane >> 4;
  const int jbase = jh * 4608 + (w << 6);
  const int sw   = (i16 & 3) << 2;          // P-tile granule-XOR swizzle

  unsigned short* pb = &p_lds[w * 4608];

  const unsigned short* __restrict__ vb = vg + (size_t)b * 64 * NTOK;
  const unsigned short* __restrict__ kb = kg + (size_t)b * NTOK * 8;
  const int koff = i16 * 8;
  const int voff = i16 * NTOK + quad * 8;

  bf16x8 qf[2] = {};
  if (quad == 0) {
    qf[0] = *(const bf16x8*)(qg + ((size_t)b * NTOK + rt * 32 + i16) * 8);
    qf[1] = *(const bf16x8*)(qg + ((size_t)b * NTOK + rt * 32 + 16 + i16) * 8);
  }

  f32x4 acc[2][4], accl[2];
  #pragma unroll
  for (int s = 0; s < 2; s++) {
    #pragma unroll
    for (int ct = 0; ct < 4; ct++) acc[s][ct] = (f32x4){0.f, 0.f, 0.f, 0.f};
    accl[s] = (f32x4){0.f, 0.f, 0.f, 0.f};
  }
  const f32x4 z4 = {0.f, 0.f, 0.f, 0.f};
  const short one_bf = (short)0x3F80;      // bf16 1.0
  const bf16x8 onef = {one_bf, one_bf, one_bf, one_bf,
                       one_bf, one_bf, one_bf, one_bf};

  bf16x8 kfA[4], kfB[4];
  #pragma unroll
  for (int jt = 0; jt < 4; jt++)
    kfA[jt] = *(const bf16x8*)(kb + (jbase + jt * 16) * 8 + koff);

  STAGE(0, kfA, kfB, jbase + 256);
  for (int it2 = 0; it2 < 8; ++it2) {
    BODY(2 * it2 + 1, kfB, kfA);
    BODY(2 * it2 + 2, kfA, kfB);
  }
  BODY(17, kfB, kfA);

  // epilogue: PV(17) + l(17)
  {
    const int jp = jbase + (17 << 8);
    unsigned short* pr = pb + 2304;   // buffer 17&1
    #pragma unroll
    for (int s = 0; s < 2; s++) {
      bf16x8 pf0 = *(const bf16x8*)(&pr[(s * 16 + i16) * 72 + (((2 * quad) ^ sw) << 2)]);
      bf16x8 pf1 = *(const bf16x8*)(&pr[(s * 16 + i16) * 72 + (((8 + 2 * quad) ^ sw) << 2)]);
      #pragma unroll
      for (int ct = 0; ct < 4; ct++) {
        bf16x8 vf0 = *(const bf16x8*)(vb + ct * 16 * NTOK + voff + jp);
        bf16x8 vf1 = *(const bf16x8*)(vb + ct * 16 * NTOK + voff + jp + 32);
        acc[s][ct] = __builtin_amdgcn_mfma_f32_16x16x32_bf16(vf0, pf0, acc[s][ct], 0, 0, 0);
        acc[s][ct] = __builtin_amdgcn_mfma_f32_16x16x32_bf16(vf1, pf1, acc[s][ct], 0, 0, 0);
      }
      accl[s] = __builtin_amdgcn_mfma_f32_16x16x32_bf16(onef, pf0, accl[s], 0, 0, 0);
      accl[s] = __builtin_amdgcn_mfma_f32_16x16x32_bf16(onef, pf1, accl[s], 0, 0, 0);
    }
  }

  // l per row: every C/D row of ones·P^T holds the same row-sum -> reg 0
  if (quad == 0) { l_s[w][i16] = accl[0][0]; l_s[w][16 + i16] = accl[1][0]; }

  __syncthreads();                 // all P-tile reads done -> overlay obuf
  float* obuf = (float*)p_lds;     // [4][64][33] = 33792 B <= 36864 B
  #pragma unroll
  for (int s = 0; s < 2; s++)
    #pragma unroll
    for (int ct = 0; ct < 4; ct++)
      #pragma unroll
      for (int r = 0; r < 4; r++)
        obuf[w * 2112 + (ct * 16 + quad * 4 + r) * 33 + s * 16 + i16] = acc[s][ct][r];
  __syncthreads();

  float* ob = opart + (size_t)bid * 2048;
  #pragma unroll
  for (int e0 = 0; e0 < 8; e0++) {
    int e = tid + e0 * 256, c = e >> 5, r = e & 31;
    ob[e] = obuf[c * 33 + r] + obuf[2112 + c * 33 + r]
          + obuf[4224 + c * 33 + r] + obuf[6336 + c * 33 + r];
  }
  if (tid < 32)
    lpart[(size_t)bid * 32 + tid] =
        l_s[0][tid] + l_s[1][tid] + l_s[2][tid] + l_s[3][tid];
}

// ---------------------------------------------------------------------------
// Kernel 3: merge the 2 j-half partials + epilogue: y = gs*O/L + x
// ---------------------------------------------------------------------------
__global__ __launch_bounds__(256) void reduce_ep(
    const float* __restrict__ x,
    const float* __restrict__ opart, const float* __restrict__ lpart,
    const float* __restrict__ gamma_p, const float* __restrict__ dyn_p,
    float* __restrict__ y)
{
  const int bid = blockIdx.x;            // b*288 + rt
  const int b = bid / 288, rt = bid % 288;
  const int tid = threadIdx.x;
  const float gs = gamma_p[0] * dyn_p[0];
  const float* o0 = opart + (size_t)(bid * 2) * 2048;
  const float* o1 = o0 + 2048;
  const float* l0 = lpart + (size_t)(bid * 2) * 32;
  const float* l1 = l0 + 32;
  #pragma unroll
  for (int e0 = 0; e0 < 8; e0++) {
    int e = tid + e0 * 256, c = e >> 5, r = e & 31;
    float L = l0[r] + l1[r];
    float O = o0[e] + o1[e];
    size_t a = (size_t)(b * 64 + c) * NTOK + rt * 32 + r;
    y[a] = gs * O / L + x[a];
  }
}

// ---------------------------------------------------------------------------
extern "C" void kernel_launch(void* const* d_in, const int* in_sizes, int n_in,
                              void* d_out, int out_size, void* d_ws, size_t ws_size,
                              hipStream_t stream) {
  const float* x     = (const float*)d_in[0];
  const float* Wq    = (const float*)d_in[1];
  const float* bq    = (const float*)d_in[2];
  const float* Wk    = (const float*)d_in[3];
  const float* bk    = (const float*)d_in[4];
  const float* Wv    = (const float*)d_in[5];
  const float* bv    = (const float*)d_in[6];
  const float* gamma = (const float*)d_in[7];
  const float* dyn   = (const float*)d_in[8];
  float* y = (float*)d_out;

  // workspace layout (bf16 then f32, 16B-aligned boundaries)
  unsigned short* qg = (unsigned short*)d_ws;              // B*N*8
  unsigned short* kg = qg + (size_t)NBAT * NTOK * 8;       // B*N*8
  unsigned short* vg = kg + (size_t)NBAT * NTOK * 8;       // B*64*N
  float* opart = (float*)(vg + (size_t)NBAT * 64 * NTOK);  // 1152*2048
  float* lpart = opart + (size_t)1152 * 2048;              // 1152*32

  qkv_proj<<<NBAT * 144 * 5, 256, 0, stream>>>(x, Wq, bq, Wk, bk, Wv, bv, qg, kg, vg);
  flash_partial<<<NBAT * 288 * 2, 256, 0, stream>>>(qg, kg, vg, opart, lpart);
  reduce_ep<<<NBAT * 288, 256, 0, stream>>>(x, opart, lpart, gamma, dyn, y);
}